// Round 4
// baseline (231.406 us; speedup 1.0000x reference)
//
#include <hip/hip_runtime.h>

// TranslationLayer: out[b,i,j] = in[b, i+dy[b], j-dx[b]] if in-bounds else 0
// B,H,W,C = 128,512,512,1 fp32. Pure memory-bound shift-gather.
//
// R4: one WAVE per output row (2 KB). Lane L handles float4 groups {L, L+64}:
// 2 aligned dwordx4 loads + 2 NT dwordx4 stores per lane -> 2x bytes in
// flight per wave, half the wave count vs R3. dx/dy/q/r are wave-uniform.
// Funnel shift by r=(-dx)&3 via cross-lane shuffles; lane63/part1's neighbor
// is lane0's part-2 register (shfl, no load); only lane63/part2 with q<0
// needs a 1-lane predicated load. Aligned 4-float groups are fully in- or
// out-of-range, so element zero-fill reduces exactly to group zero-fill.
//
// Evidence note (R3 post-mortem): harness dur_us includes ~145us of reset
// traffic (537MB ws-poison fills at 6.7 TB/s dominate the dispatch table);
// the kernel dispatch itself is <78us. Target: ~45us kernel.

#define TB 128
#define TH 512
#define TW 512
#define W4 (TW / 4)   // 128 float4 groups per row

typedef float f4 __attribute__((ext_vector_type(4)));

__device__ __forceinline__ f4 funnel(const f4 v, const f4 n, const int r) {
    f4 o;
    if (r == 1)      { o.x = v.y; o.y = v.z; o.z = v.w; o.w = n.x; }
    else if (r == 2) { o.x = v.z; o.y = v.w; o.z = n.x; o.w = n.y; }
    else             { o.x = v.w; o.y = n.x; o.z = n.y; o.w = n.z; }
    return o;
}

__global__ __launch_bounds__(256) void TranslationLayer_63350767616318_kernel(
    const float* __restrict__ in,
    const int*   __restrict__ dx,
    const int*   __restrict__ dy,
    float*       __restrict__ out)
{
    const int gtid = blockIdx.x * blockDim.x + threadIdx.x;
    const int wave = gtid >> 6;          // one wave per output row
    const int L    = threadIdx.x & 63;   // lane
    const int i    = wave & (TH - 1);    // output row within sample
    const int b    = wave >> 9;          // sample

    const int si = i + dy[b];

    f4 o1 = (f4)(0.f);
    f4 o2 = (f4)(0.f);

    if (si >= 0 && si < TH) {            // wave-uniform at runtime
        const f4* __restrict__ row4 =
            (const f4*)(in + ((size_t)(b * TH + si)) * TW);
        const int t = -dx[b];
        const int q = t >> 2;            // uniform group offset, q in [-10,10]
        const int r = t & 3;             // uniform residue
        const int s1 = L + q;            // source group for part 1
        const int s2 = L + 64 + q;       // source group for part 2

        f4 v1 = (f4)(0.f);
        f4 v2 = (f4)(0.f);
        if ((unsigned)s1 < (unsigned)W4) v1 = row4[s1];
        if ((unsigned)s2 < (unsigned)W4) v2 = row4[s2];

        if (r == 0) {
            o1 = v1;
            o2 = v2;
        } else {
            // neighbor groups A[s+1] via cross-lane pulls (no memory)
            f4 n1, n2, w0;
            n1.x = __shfl_down(v1.x, 1); n1.y = __shfl_down(v1.y, 1);
            n1.z = __shfl_down(v1.z, 1); n1.w = __shfl_down(v1.w, 1);
            n2.x = __shfl_down(v2.x, 1); n2.y = __shfl_down(v2.y, 1);
            n2.z = __shfl_down(v2.z, 1); n2.w = __shfl_down(v2.w, 1);
            // lane0's part-2 value = A[64+q], needed by lane63 part 1
            w0.x = __shfl(v2.x, 0); w0.y = __shfl(v2.y, 0);
            w0.z = __shfl(v2.z, 0); w0.w = __shfl(v2.w, 0);
            if (L == 63) {
                n1 = w0;
                n2 = (f4)(0.f);
                const int s3 = 128 + q;          // only valid when q < 0
                if ((unsigned)s3 < (unsigned)W4) n2 = row4[s3];
            }
            o1 = funnel(v1, n1, r);
            o2 = funnel(v2, n2, r);
        }
    }

    f4* __restrict__ orow = (f4*)out + (size_t)wave * W4;
    __builtin_nontemporal_store(o1, orow + L);
    __builtin_nontemporal_store(o2, orow + L + 64);
}

extern "C" void kernel_launch(void* const* d_in, const int* in_sizes, int n_in,
                              void* d_out, int out_size, void* d_ws, size_t ws_size,
                              hipStream_t stream)
{
    const float* in  = (const float*)d_in[0];
    const int*   dx  = (const int*)d_in[1];
    const int*   dy  = (const int*)d_in[2];
    float*       out = (float*)d_out;

    // rows = 128*512 = 65536 waves; 4 waves/block -> 16384 blocks of 256
    const int nrows  = TB * TH;
    dim3 grid(nrows / 4), block(256);
    TranslationLayer_63350767616318_kernel<<<grid, block, 0, stream>>>(in, dx, dy, out);
}